// Round 4
// baseline (309.918 us; speedup 1.0000x reference)
//
#include <hip/hip_runtime.h>

// Problem constants (from reference)
#define B_  4
#define N_  1
#define D_  48
#define H_  32
#define W_  88
#define C_  64
#define NX_ 200
#define NY_ 200
#define NZ_ 1
#define NPRIME (B_ * N_ * D_ * H_ * W_)   // 540,672 points (< 2^20)
#define NXY    (NX_ * NY_)                // 40,000 bev cells
#define NVOX   (B_ * NXY)                 // 160,000 voxels = 2500 * 64

#define PMASK 0xFFFFF                     // low 20 bits = point id

// ---------------------------------------------------------------------------
// Kernel 1: per-point voxel id + histogram. One thread per point.
// ---------------------------------------------------------------------------
__global__ __launch_bounds__(256)
void hist_kernel(const float* __restrict__ geom,
                 const float* __restrict__ sem,
                 const float* __restrict__ dxp,
                 const float* __restrict__ bxp,
                 int* __restrict__ voxid,
                 int* __restrict__ counts)
{
    int p = blockIdx.x * 256 + threadIdx.x;   // NPRIME = 2112*256 exactly
    // p -> (b, d, h, w), N = 1
    int w = p % W_;
    int t = p / W_;
    int h = t % H_;
    t /= H_;                   // t = b*D + d
    int b = t / D_;

    int v = -1;
    float sm = sem[(b * 2 + 1) * (H_ * W_) + h * W_ + w];
    if (sm > 0.5f) {
        // match reference f32 arithmetic: (geom - (bx - dx/2)) / dx, trunc to 0
        float gxf = (geom[(size_t)p * 3 + 0] - (bxp[0] - dxp[0] * 0.5f)) / dxp[0];
        float gyf = (geom[(size_t)p * 3 + 1] - (bxp[1] - dxp[1] * 0.5f)) / dxp[1];
        float gzf = (geom[(size_t)p * 3 + 2] - (bxp[2] - dxp[2] * 0.5f)) / dxp[2];
        int gx = (int)gxf, gy = (int)gyf, gz = (int)gzf;
        if (gx >= 0 && gx < NX_ && gy >= 0 && gy < NY_ &&
            gz >= 0 && gz < NZ_) {
            v = b * NXY + gx * NY_ + gy;   // NZ==1 so gz==0
            atomicAdd(&counts[v], 1);
        }
    }
    voxid[p] = v;
}

// ---------------------------------------------------------------------------
// Scan pass 1: per-block (256-wide) exclusive scan of counts -> base,
// block totals -> partials. 625 blocks.
// ---------------------------------------------------------------------------
__global__ __launch_bounds__(256)
void scan1_kernel(const int* __restrict__ counts,
                  int* __restrict__ base,
                  int* __restrict__ partials)
{
    __shared__ int s[256];
    int t = threadIdx.x;
    int i = blockIdx.x * 256 + t;
    int c = counts[i];
    s[t] = c;
    __syncthreads();
    for (int off = 1; off < 256; off <<= 1) {
        int add = (t >= off) ? s[t - off] : 0;
        __syncthreads();
        s[t] += add;
        __syncthreads();
    }
    base[i] = s[t] - c;                 // exclusive within block
    if (t == 255) partials[blockIdx.x] = s[255];
}

// ---------------------------------------------------------------------------
// Scan pass 2: inclusive scan of 625 partials in one block (in-place).
// Also writes base[NVOX] = grand total.
// ---------------------------------------------------------------------------
__global__ __launch_bounds__(1024)
void scan2_kernel(int* __restrict__ partials, int* __restrict__ base)
{
    __shared__ int s[1024];
    int t = threadIdx.x;
    s[t] = (t < 625) ? partials[t] : 0;
    __syncthreads();
    for (int off = 1; off < 1024; off <<= 1) {
        int add = (t >= off) ? s[t - off] : 0;
        __syncthreads();
        s[t] += add;
        __syncthreads();
    }
    if (t < 625) partials[t] = s[t];    // inclusive scan
    if (t == 624) base[NVOX] = s[624];  // grand total
}

// ---------------------------------------------------------------------------
// Scan pass 3: add block offsets; init cursor = base.
// ---------------------------------------------------------------------------
__global__ __launch_bounds__(256)
void scan3_kernel(int* __restrict__ base,
                  const int* __restrict__ partials,
                  int* __restrict__ cursor)
{
    int blk = blockIdx.x;
    int i = blk * 256 + threadIdx.x;
    int off = (blk > 0) ? partials[blk - 1] : 0;
    int bv = base[i] + off;
    base[i] = bv;
    cursor[i] = bv;
}

// ---------------------------------------------------------------------------
// Kernel 5: fill per-voxel point lists. Entry packs (v%64)<<20 | p so the
// gather needs no voxid lookup. (v%64 == local voxel index within the
// gather block, since gather blocks own 64-aligned voxel ranges.)
// ---------------------------------------------------------------------------
__global__ __launch_bounds__(256)
void fill_kernel(const int* __restrict__ voxid,
                 int* __restrict__ cursor,
                 int* __restrict__ plist)
{
    int p = blockIdx.x * 256 + threadIdx.x;
    int v = voxid[p];
    if (v >= 0) {
        int slot = atomicAdd(&cursor[v], 1);
        plist[slot] = ((v & 63) << 20) | p;
    }
}

// ---------------------------------------------------------------------------
// Kernel 6: gather + fused transpose. Block = 256 thr (4 waves) owns 64
// consecutive voxels (one contiguous plist range, ~109 points avg). The 4
// waves jointly stride the point range — iterations are INDEPENDENT, 4-deep
// manual unroll keeps 4 coalesced 256 B x-loads in flight per wave —
// accumulating into the LDS tile via LDS atomics. Then LDS transpose and
// coalesced (B,C,X,Y) store.
// ---------------------------------------------------------------------------
__global__ __launch_bounds__(256)
void gather_kernel(const float* __restrict__ x,
                   const int* __restrict__ base,
                   const int* __restrict__ plist,
                   float* __restrict__ out)
{
    __shared__ float tile[64][65];      // [vox][ch], +1 pad
    int blk = blockIdx.x;               // 0..2499
    int t    = threadIdx.x;
    int wave = t >> 6;
    int lane = t & 63;                  // channel
    int vbase = blk * 64;
    int b   = vbase / NXY;
    int xy0 = vbase % NXY;

    // zero the FULL tile (64*65 = 4160 floats — round-3 bug was zeroing
    // only 4096, leaving row 63 cols 1..64 as garbage under atomicAdd)
    for (int i = t; i < 64 * 65; i += 256)
        ((float*)tile)[i] = 0.f;
    __syncthreads();

    int J0 = base[vbase];
    int J1 = base[vbase + 64];

    int j = J0 + wave;
    // 4-deep unrolled: entries j, j+4, j+8, j+12 (wave stride 4)
    for (; j + 12 < J1; j += 16) {
        int e0 = plist[j];
        int e1 = plist[j + 4];
        int e2 = plist[j + 8];
        int e3 = plist[j + 12];
        float v0 = x[(size_t)(e0 & PMASK) * C_ + lane];
        float v1 = x[(size_t)(e1 & PMASK) * C_ + lane];
        float v2 = x[(size_t)(e2 & PMASK) * C_ + lane];
        float v3 = x[(size_t)(e3 & PMASK) * C_ + lane];
        atomicAdd(&tile[e0 >> 20][lane], v0);
        atomicAdd(&tile[e1 >> 20][lane], v1);
        atomicAdd(&tile[e2 >> 20][lane], v2);
        atomicAdd(&tile[e3 >> 20][lane], v3);
    }
    for (; j < J1; j += 4) {
        int e = plist[j];
        float v = x[(size_t)(e & PMASK) * C_ + lane];
        atomicAdd(&tile[e >> 20][lane], v);
    }
    __syncthreads();

    // transpose out: lane group writes 256 B contiguous runs of (B,C,XY)
    int col = t & 63;                   // xy within tile
    int rg  = t >> 6;                   // 0..3
    float* dst = out + (size_t)b * C_ * NXY + xy0;
    for (int it = 0; it < 16; ++it) {
        int ch = it * 4 + rg;
        dst[(size_t)ch * NXY + col] = tile[col][ch];
    }
}

// ---------------------------------------------------------------------------
// Fallback (ws tiny): direct strided atomics into out (B, C, NX, NY).
// ---------------------------------------------------------------------------
__global__ __launch_bounds__(256)
void scatter_direct(const float* __restrict__ x,
                    const float* __restrict__ geom,
                    const float* __restrict__ sem,
                    const float* __restrict__ dxp,
                    const float* __restrict__ bxp,
                    float* __restrict__ out)
{
    int gid = blockIdx.x * 256 + threadIdx.x;
    int p = gid >> 6;
    int c = gid & 63;
    if (p >= NPRIME) return;
    int w = p % W_;
    int t = p / W_;
    int h = t % H_;
    t /= H_;
    int b = t / D_;
    float sm = sem[(b * 2 + 1) * (H_ * W_) + h * W_ + w];
    if (!(sm > 0.5f)) return;
    float gxf = (geom[(size_t)p * 3 + 0] - (bxp[0] - dxp[0] * 0.5f)) / dxp[0];
    float gyf = (geom[(size_t)p * 3 + 1] - (bxp[1] - dxp[1] * 0.5f)) / dxp[1];
    float gzf = (geom[(size_t)p * 3 + 2] - (bxp[2] - dxp[2] * 0.5f)) / dxp[2];
    int gx = (int)gxf, gy = (int)gyf, gz = (int)gzf;
    if (gx < 0 || gx >= NX_ || gy < 0 || gy >= NY_ ||
        gz < 0 || gz >= NZ_) return;
    float val = x[(size_t)p * C_ + c];
    atomicAdd(&out[(((size_t)b * C_ + c) * NX_ + gx) * NY_ + gy], val);
}

// ---------------------------------------------------------------------------
extern "C" void kernel_launch(void* const* d_in, const int* in_sizes, int n_in,
                              void* d_out, int out_size, void* d_ws, size_t ws_size,
                              hipStream_t stream)
{
    const float* x    = (const float*)d_in[0];   // (B,N,D,H,W,C)
    const float* geom = (const float*)d_in[1];   // (B,N,D,H,W,3)
    const float* sem  = (const float*)d_in[2];   // (B*N,2,H,W)
    const float* dxp  = (const float*)d_in[3];   // (3,)
    const float* bxp  = (const float*)d_in[4];   // (3,)
    float* out = (float*)d_out;                  // (B, C, NX, NY)

    // ws layout (1 MiB-aligned regions; total need ~10.5 MiB)
    char* wsb = (char*)d_ws;
    const size_t MB = 1024 * 1024;
    int* counts   = (int*)(wsb + 0 * MB);   // NVOX ints        (640 KB)
    int* base     = (int*)(wsb + 1 * MB);   // NVOX+1 ints      (640 KB)
    int* cursor   = (int*)(wsb + 2 * MB);   // NVOX ints        (640 KB)
    int* partials = (int*)(wsb + 3 * MB);   // 625 ints
    int* voxid    = (int*)(wsb + 4 * MB);   // NPRIME ints      (2.1 MB)
    int* plist    = (int*)(wsb + 7 * MB);   // NPRIME ints      (2.1 MB)
    const size_t wsNeed = 10 * MB;

    if (ws_size >= wsNeed) {
        hipMemsetAsync(counts, 0, (size_t)NVOX * sizeof(int), stream);
        hist_kernel<<<NPRIME / 256, 256, 0, stream>>>(geom, sem, dxp, bxp,
                                                      voxid, counts);
        scan1_kernel<<<NVOX / 256, 256, 0, stream>>>(counts, base, partials);
        scan2_kernel<<<1, 1024, 0, stream>>>(partials, base);
        scan3_kernel<<<NVOX / 256, 256, 0, stream>>>(base, partials, cursor);
        fill_kernel<<<NPRIME / 256, 256, 0, stream>>>(voxid, cursor, plist);
        gather_kernel<<<NVOX / 64, 256, 0, stream>>>(x, base, plist, out);
    } else {
        hipMemsetAsync(out, 0, (size_t)B_ * C_ * NXY * sizeof(float), stream);
        int nBlocks = (NPRIME * 64 + 255) / 256;
        scatter_direct<<<nBlocks, 256, 0, stream>>>(x, geom, sem, dxp, bxp, out);
    }
}

// Round 5
// 253.878 us; speedup vs baseline: 1.2207x; 1.2207x over previous
//
#include <hip/hip_runtime.h>

// Problem constants (from reference)
#define B_  4
#define N_  1
#define D_  48
#define H_  32
#define W_  88
#define C_  64
#define NX_ 200
#define NY_ 200
#define NZ_ 1
#define NPRIME (B_ * N_ * D_ * H_ * W_)   // 540,672 points
#define NXY    (NX_ * NY_)                // 40,000 bev cells
#define NVOX   (B_ * NXY)                 // 160,000 voxels = 2500 * 64

// ---------------------------------------------------------------------------
// Kernel 1: per-point voxel id + histogram. One thread per point.
// ---------------------------------------------------------------------------
__global__ __launch_bounds__(256)
void hist_kernel(const float* __restrict__ geom,
                 const float* __restrict__ sem,
                 const float* __restrict__ dxp,
                 const float* __restrict__ bxp,
                 int* __restrict__ voxid,
                 int* __restrict__ counts)
{
    int p = blockIdx.x * 256 + threadIdx.x;   // NPRIME = 2112*256 exactly
    int w = p % W_;
    int t = p / W_;
    int h = t % H_;
    t /= H_;                   // t = b*D + d
    int b = t / D_;

    int v = -1;
    float sm = sem[(b * 2 + 1) * (H_ * W_) + h * W_ + w];
    if (sm > 0.5f) {
        // match reference f32 arithmetic: (geom - (bx - dx/2)) / dx, trunc to 0
        float gxf = (geom[(size_t)p * 3 + 0] - (bxp[0] - dxp[0] * 0.5f)) / dxp[0];
        float gyf = (geom[(size_t)p * 3 + 1] - (bxp[1] - dxp[1] * 0.5f)) / dxp[1];
        float gzf = (geom[(size_t)p * 3 + 2] - (bxp[2] - dxp[2] * 0.5f)) / dxp[2];
        int gx = (int)gxf, gy = (int)gyf, gz = (int)gzf;
        if (gx >= 0 && gx < NX_ && gy >= 0 && gy < NY_ &&
            gz >= 0 && gz < NZ_) {
            v = b * NXY + gx * NY_ + gy;   // NZ==1 so gz==0
            atomicAdd(&counts[v], 1);
        }
    }
    voxid[p] = v;
}

// ---------------------------------------------------------------------------
// Scan pass 1: per-block (256-wide) exclusive scan of counts -> base,
// block totals -> partials. 625 blocks.
// ---------------------------------------------------------------------------
__global__ __launch_bounds__(256)
void scan1_kernel(const int* __restrict__ counts,
                  int* __restrict__ base,
                  int* __restrict__ partials)
{
    __shared__ int s[256];
    int t = threadIdx.x;
    int i = blockIdx.x * 256 + t;
    int c = counts[i];
    s[t] = c;
    __syncthreads();
    for (int off = 1; off < 256; off <<= 1) {
        int add = (t >= off) ? s[t - off] : 0;
        __syncthreads();
        s[t] += add;
        __syncthreads();
    }
    base[i] = s[t] - c;                 // exclusive within block
    if (t == 255) partials[blockIdx.x] = s[255];
}

// ---------------------------------------------------------------------------
// Scan pass 2: inclusive scan of 625 partials in one block (in-place).
// ---------------------------------------------------------------------------
__global__ __launch_bounds__(1024)
void scan2_kernel(int* __restrict__ partials, int* __restrict__ base)
{
    __shared__ int s[1024];
    int t = threadIdx.x;
    s[t] = (t < 625) ? partials[t] : 0;
    __syncthreads();
    for (int off = 1; off < 1024; off <<= 1) {
        int add = (t >= off) ? s[t - off] : 0;
        __syncthreads();
        s[t] += add;
        __syncthreads();
    }
    if (t < 625) partials[t] = s[t];    // inclusive scan
    if (t == 624) base[NVOX] = s[624];  // grand total
}

// ---------------------------------------------------------------------------
// Scan pass 3: add block offsets; init cursor = base.
// ---------------------------------------------------------------------------
__global__ __launch_bounds__(256)
void scan3_kernel(int* __restrict__ base,
                  const int* __restrict__ partials,
                  int* __restrict__ cursor)
{
    int blk = blockIdx.x;
    int i = blk * 256 + threadIdx.x;
    int off = (blk > 0) ? partials[blk - 1] : 0;
    int bv = base[i] + off;
    base[i] = bv;
    cursor[i] = bv;
}

// ---------------------------------------------------------------------------
// Kernel 5: fill per-voxel point lists (plain point id).
// ---------------------------------------------------------------------------
__global__ __launch_bounds__(256)
void fill_kernel(const int* __restrict__ voxid,
                 int* __restrict__ cursor,
                 int* __restrict__ plist)
{
    int p = blockIdx.x * 256 + threadIdx.x;
    int v = voxid[p];
    if (v >= 0) {
        int slot = atomicAdd(&cursor[v], 1);
        plist[slot] = p;
    }
}

// ---------------------------------------------------------------------------
// Kernel 6: gather + fused transpose, HIGH-MLP version.
// Block = 256 thr (4 waves) owns 64 voxels; each wave owns 16 voxels as 16
// INDEPENDENT chains processed in lock-step rounds. Round r: 16 unconditional
// plist loads (always-valid addresses, masked afterward), 16 independent
// 256 B x-loads, 16 masked register adds. ~16 loads in flight per phase per
// wave instead of ~4. No atomics. Then LDS transpose, coalesced store.
// ---------------------------------------------------------------------------
__global__ __launch_bounds__(256)
void gather_kernel(const float* __restrict__ x,
                   const int* __restrict__ base,
                   const int* __restrict__ plist,
                   float* __restrict__ out)
{
    __shared__ float tile[64][65];      // [vox][ch], +1 pad
    int blk = blockIdx.x;               // 0..2499
    int t    = threadIdx.x;
    int wave = t >> 6;
    int lane = t & 63;                  // channel
    int vbase = blk * 64;
    int b   = vbase / NXY;
    int xy0 = vbase % NXY;

    int v0 = vbase + wave * 16;         // this wave's 16 voxels
    int j0[16], cnt[16];
    #pragma unroll
    for (int i = 0; i < 16; ++i) j0[i] = base[v0 + i];
    int jend = base[v0 + 16];
    #pragma unroll
    for (int i = 0; i < 16; ++i)
        cnt[i] = ((i < 15) ? j0[i + 1] : jend) - j0[i];

    int rmax = 0;
    #pragma unroll
    for (int i = 0; i < 16; ++i) rmax = max(rmax, cnt[i]);

    float acc[16];
    #pragma unroll
    for (int i = 0; i < 16; ++i) acc[i] = 0.f;

    for (int r = 0; r < rmax; ++r) {
        int e[16];
        #pragma unroll
        for (int i = 0; i < 16; ++i) {
            // address always valid: j0+r < total + rmax, plist region has slack
            int tmp = plist[j0[i] + r];
            e[i] = (r < cnt[i]) ? tmp : 0;          // dead chain -> point 0
        }
        float val[16];
        #pragma unroll
        for (int i = 0; i < 16; ++i)
            val[i] = x[(size_t)e[i] * C_ + lane];   // dead chain: x[lane], L1-hot
        #pragma unroll
        for (int i = 0; i < 16; ++i)
            acc[i] += (r < cnt[i]) ? val[i] : 0.f;
    }

    #pragma unroll
    for (int i = 0; i < 16; ++i)
        tile[wave * 16 + i][lane] = acc[i];
    __syncthreads();

    // transpose out: lane group writes 256 B contiguous runs of (B,C,XY)
    int col = t & 63;                   // xy within tile
    int rg  = t >> 6;                   // 0..3
    float* dst = out + (size_t)b * C_ * NXY + xy0;
    #pragma unroll
    for (int it = 0; it < 16; ++it) {
        int ch = it * 4 + rg;
        dst[(size_t)ch * NXY + col] = tile[col][ch];
    }
}

// ---------------------------------------------------------------------------
// Fallback (ws tiny): direct strided atomics into out (B, C, NX, NY).
// ---------------------------------------------------------------------------
__global__ __launch_bounds__(256)
void scatter_direct(const float* __restrict__ x,
                    const float* __restrict__ geom,
                    const float* __restrict__ sem,
                    const float* __restrict__ dxp,
                    const float* __restrict__ bxp,
                    float* __restrict__ out)
{
    int gid = blockIdx.x * 256 + threadIdx.x;
    int p = gid >> 6;
    int c = gid & 63;
    if (p >= NPRIME) return;
    int w = p % W_;
    int t = p / W_;
    int h = t % H_;
    t /= H_;
    int b = t / D_;
    float sm = sem[(b * 2 + 1) * (H_ * W_) + h * W_ + w];
    if (!(sm > 0.5f)) return;
    float gxf = (geom[(size_t)p * 3 + 0] - (bxp[0] - dxp[0] * 0.5f)) / dxp[0];
    float gyf = (geom[(size_t)p * 3 + 1] - (bxp[1] - dxp[1] * 0.5f)) / dxp[1];
    float gzf = (geom[(size_t)p * 3 + 2] - (bxp[2] - dxp[2] * 0.5f)) / dxp[2];
    int gx = (int)gxf, gy = (int)gyf, gz = (int)gzf;
    if (gx < 0 || gx >= NX_ || gy < 0 || gy >= NY_ ||
        gz < 0 || gz >= NZ_) return;
    float val = x[(size_t)p * C_ + c];
    atomicAdd(&out[(((size_t)b * C_ + c) * NX_ + gx) * NY_ + gy], val);
}

// ---------------------------------------------------------------------------
extern "C" void kernel_launch(void* const* d_in, const int* in_sizes, int n_in,
                              void* d_out, int out_size, void* d_ws, size_t ws_size,
                              hipStream_t stream)
{
    const float* x    = (const float*)d_in[0];   // (B,N,D,H,W,C)
    const float* geom = (const float*)d_in[1];   // (B,N,D,H,W,3)
    const float* sem  = (const float*)d_in[2];   // (B*N,2,H,W)
    const float* dxp  = (const float*)d_in[3];   // (3,)
    const float* bxp  = (const float*)d_in[4];   // (3,)
    float* out = (float*)d_out;                  // (B, C, NX, NY)

    // ws layout (1 MiB-aligned regions; total need ~10.5 MiB)
    char* wsb = (char*)d_ws;
    const size_t MB = 1024 * 1024;
    int* counts   = (int*)(wsb + 0 * MB);   // NVOX ints        (640 KB)
    int* base     = (int*)(wsb + 1 * MB);   // NVOX+1 ints      (640 KB)
    int* cursor   = (int*)(wsb + 2 * MB);   // NVOX ints        (640 KB)
    int* partials = (int*)(wsb + 3 * MB);   // 625 ints
    int* voxid    = (int*)(wsb + 4 * MB);   // NPRIME ints      (2.1 MB)
    int* plist    = (int*)(wsb + 7 * MB);   // NPRIME ints      (2.1 MB), slack after
    const size_t wsNeed = 10 * MB;

    if (ws_size >= wsNeed) {
        hipMemsetAsync(counts, 0, (size_t)NVOX * sizeof(int), stream);
        hist_kernel<<<NPRIME / 256, 256, 0, stream>>>(geom, sem, dxp, bxp,
                                                      voxid, counts);
        scan1_kernel<<<NVOX / 256, 256, 0, stream>>>(counts, base, partials);
        scan2_kernel<<<1, 1024, 0, stream>>>(partials, base);
        scan3_kernel<<<NVOX / 256, 256, 0, stream>>>(base, partials, cursor);
        fill_kernel<<<NPRIME / 256, 256, 0, stream>>>(voxid, cursor, plist);
        gather_kernel<<<NVOX / 64, 256, 0, stream>>>(x, base, plist, out);
    } else {
        hipMemsetAsync(out, 0, (size_t)B_ * C_ * NXY * sizeof(float), stream);
        int nBlocks = (NPRIME * 64 + 255) / 256;
        scatter_direct<<<nBlocks, 256, 0, stream>>>(x, geom, sem, dxp, bxp, out);
    }
}

// Round 7
// 252.012 us; speedup vs baseline: 1.2298x; 1.0074x over previous
//
#include <hip/hip_runtime.h>

// Problem constants (from reference)
#define B_  4
#define N_  1
#define D_  48
#define H_  32
#define W_  88
#define C_  64
#define NX_ 200
#define NY_ 200
#define NZ_ 1
#define NPRIME (B_ * N_ * D_ * H_ * W_)   // 540,672 points
#define NXY    (NX_ * NY_)                // 40,000 bev cells
#define NVOX   (B_ * NXY)                 // 160,000 voxels = 2500 * 64

// ---------------------------------------------------------------------------
// Kernel 1: per-point voxel id + histogram. One thread per point.
// ---------------------------------------------------------------------------
__global__ __launch_bounds__(256)
void hist_kernel(const float* __restrict__ geom,
                 const float* __restrict__ sem,
                 const float* __restrict__ dxp,
                 const float* __restrict__ bxp,
                 int* __restrict__ voxid,
                 int* __restrict__ counts)
{
    int p = blockIdx.x * 256 + threadIdx.x;   // NPRIME = 2112*256 exactly
    int w = p % W_;
    int t = p / W_;
    int h = t % H_;
    t /= H_;                   // t = b*D + d
    int b = t / D_;

    int v = -1;
    float sm = sem[(b * 2 + 1) * (H_ * W_) + h * W_ + w];
    if (sm > 0.5f) {
        // match reference f32 arithmetic: (geom - (bx - dx/2)) / dx, trunc to 0
        float gxf = (geom[(size_t)p * 3 + 0] - (bxp[0] - dxp[0] * 0.5f)) / dxp[0];
        float gyf = (geom[(size_t)p * 3 + 1] - (bxp[1] - dxp[1] * 0.5f)) / dxp[1];
        float gzf = (geom[(size_t)p * 3 + 2] - (bxp[2] - dxp[2] * 0.5f)) / dxp[2];
        int gx = (int)gxf, gy = (int)gyf, gz = (int)gzf;
        if (gx >= 0 && gx < NX_ && gy >= 0 && gy < NY_ &&
            gz >= 0 && gz < NZ_) {
            v = b * NXY + gx * NY_ + gy;   // NZ==1 so gz==0
            atomicAdd(&counts[v], 1);
        }
    }
    voxid[p] = v;
}

// ---------------------------------------------------------------------------
// Scan pass 1: per-block (256-wide) exclusive scan of counts -> base,
// block totals -> partials. 625 blocks.
// ---------------------------------------------------------------------------
__global__ __launch_bounds__(256)
void scan1_kernel(const int* __restrict__ counts,
                  int* __restrict__ base,
                  int* __restrict__ partials)
{
    __shared__ int s[256];
    int t = threadIdx.x;
    int i = blockIdx.x * 256 + t;
    int c = counts[i];
    s[t] = c;
    __syncthreads();
    for (int off = 1; off < 256; off <<= 1) {
        int add = (t >= off) ? s[t - off] : 0;
        __syncthreads();
        s[t] += add;
        __syncthreads();
    }
    base[i] = s[t] - c;                 // exclusive within block
    if (t == 255) partials[blockIdx.x] = s[255];
}

// ---------------------------------------------------------------------------
// Scan pass 2: inclusive scan of 625 partials in one block (in-place).
// ---------------------------------------------------------------------------
__global__ __launch_bounds__(1024)
void scan2_kernel(int* __restrict__ partials, int* __restrict__ base)
{
    __shared__ int s[1024];
    int t = threadIdx.x;
    s[t] = (t < 625) ? partials[t] : 0;
    __syncthreads();
    for (int off = 1; off < 1024; off <<= 1) {
        int add = (t >= off) ? s[t - off] : 0;
        __syncthreads();
        s[t] += add;
        __syncthreads();
    }
    if (t < 625) partials[t] = s[t];    // inclusive scan
    if (t == 624) base[NVOX] = s[624];  // grand total
}

// ---------------------------------------------------------------------------
// Scan pass 3: add block offsets; init cursor = base.
// ---------------------------------------------------------------------------
__global__ __launch_bounds__(256)
void scan3_kernel(int* __restrict__ base,
                  const int* __restrict__ partials,
                  int* __restrict__ cursor)
{
    int blk = blockIdx.x;
    int i = blk * 256 + threadIdx.x;
    int off = (blk > 0) ? partials[blk - 1] : 0;
    int bv = base[i] + off;
    base[i] = bv;
    cursor[i] = bv;
}

// ---------------------------------------------------------------------------
// Kernel 5: fill per-voxel point lists (plain point id).
// ---------------------------------------------------------------------------
__global__ __launch_bounds__(256)
void fill_kernel(const int* __restrict__ voxid,
                 int* __restrict__ cursor,
                 int* __restrict__ plist)
{
    int p = blockIdx.x * 256 + threadIdx.x;
    int v = voxid[p];
    if (v >= 0) {
        int slot = atomicAdd(&cursor[v], 1);
        plist[slot] = p;
    }
}

// ---------------------------------------------------------------------------
// Kernel 6: gather + fused transpose, grouped-float4 version (hardened).
// Block = 256 thr (4 waves) owns 64 voxels; wave owns 16 voxel-chains.
// Wave split into 4 groups of 16 lanes; group g owns chains {4k+g}.
// Per round: 4 plist dword loads + 4 float4 x-loads, all independent;
// register accumulation. ALL indices clamped provably in-bounds (no
// reliance on workspace slack). Then LDS transpose, coalesced store.
// ---------------------------------------------------------------------------
__global__ __launch_bounds__(256)
void gather_kernel(const float* __restrict__ x,
                   const int* __restrict__ base,
                   const int* __restrict__ plist,
                   float* __restrict__ out)
{
    __shared__ float tile[64][65];      // [vox][ch], +1 pad
    int blk = blockIdx.x;               // 0..2499
    int t    = threadIdx.x;
    int wave = t >> 6;
    int lane = t & 63;
    int g    = lane >> 4;               // group 0..3
    int s    = lane & 15;               // channel quad: ch 4s..4s+3
    int vbase = blk * 64;
    int b   = vbase / NXY;
    int xy0 = vbase % NXY;
    int v0 = vbase + wave * 16;         // this wave's 16 voxels

    // bases (wave-uniform values, broadcast loads, L2-hot)
    int j0[17];
    #pragma unroll
    for (int i = 0; i < 17; ++i) j0[i] = base[v0 + i];

    int rmax = 0;
    #pragma unroll
    for (int i = 0; i < 16; ++i) rmax = max(rmax, j0[i + 1] - j0[i]);

    // per-lane select of my 4 chains: chain c = 4k+g  (cndmask tree, no
    // dynamic private-array indexing -> no scratch)
    int jg[4], cg[4];
    #pragma unroll
    for (int k = 0; k < 4; ++k) {
        int a0 = j0[4 * k + 0], a1 = j0[4 * k + 1], a2 = j0[4 * k + 2];
        int a3 = j0[4 * k + 3], a4 = j0[4 * k + 4];
        int lo = (g & 2) ? ((g & 1) ? a3 : a2) : ((g & 1) ? a1 : a0);
        int hi = (g & 2) ? ((g & 1) ? a4 : a3) : ((g & 1) ? a2 : a1);
        jg[k] = lo;
        cg[k] = hi - lo;
    }

    float4 acc[4];
    #pragma unroll
    for (int k = 0; k < 4; ++k) acc[k] = make_float4(0.f, 0.f, 0.f, 0.f);

    for (int r = 0; r < rmax; ++r) {
        int e[4];
        #pragma unroll
        for (int k = 0; k < 4; ++k) {
            int idx = jg[k] + r;
            idx = min(idx, NPRIME - 1);     // provably in-bounds (dead chains)
            e[k] = plist[idx];
        }
        #pragma unroll
        for (int k = 0; k < 4; ++k) {
            e[k] = (r < cg[k]) ? e[k] : 0;  // dead chain -> point 0 (L1-hot)
            e[k] = min(max(e[k], 0), NPRIME - 1);  // defend vs poison content
        }
        float4 val[4];
        #pragma unroll
        for (int k = 0; k < 4; ++k)
            val[k] = *(const float4*)(x + (size_t)e[k] * C_ + s * 4);
        #pragma unroll
        for (int k = 0; k < 4; ++k) {
            if (r < cg[k]) {
                acc[k].x += val[k].x; acc[k].y += val[k].y;
                acc[k].z += val[k].z; acc[k].w += val[k].w;
            }
        }
    }

    // tile[row][4s..4s+3] = acc; per-instr bank usage is exactly 2-way (free)
    #pragma unroll
    for (int k = 0; k < 4; ++k) {
        int row = wave * 16 + 4 * k + g;
        tile[row][4 * s + 0] = acc[k].x;
        tile[row][4 * s + 1] = acc[k].y;
        tile[row][4 * s + 2] = acc[k].z;
        tile[row][4 * s + 3] = acc[k].w;
    }
    __syncthreads();

    // transpose out: lane group writes 256 B contiguous runs of (B,C,XY)
    int col = t & 63;                   // xy within tile
    int rg  = t >> 6;                   // 0..3
    float* dst = out + (size_t)b * C_ * NXY + xy0;
    #pragma unroll
    for (int it = 0; it < 16; ++it) {
        int ch = it * 4 + rg;
        dst[(size_t)ch * NXY + col] = tile[col][ch];
    }
}

// ---------------------------------------------------------------------------
// Fallback (ws tiny): direct strided atomics into out (B, C, NX, NY).
// ---------------------------------------------------------------------------
__global__ __launch_bounds__(256)
void scatter_direct(const float* __restrict__ x,
                    const float* __restrict__ geom,
                    const float* __restrict__ sem,
                    const float* __restrict__ dxp,
                    const float* __restrict__ bxp,
                    float* __restrict__ out)
{
    int gid = blockIdx.x * 256 + threadIdx.x;
    int p = gid >> 6;
    int c = gid & 63;
    if (p >= NPRIME) return;
    int w = p % W_;
    int t = p / W_;
    int h = t % H_;
    t /= H_;
    int b = t / D_;
    float sm = sem[(b * 2 + 1) * (H_ * W_) + h * W_ + w];
    if (!(sm > 0.5f)) return;
    float gxf = (geom[(size_t)p * 3 + 0] - (bxp[0] - dxp[0] * 0.5f)) / dxp[0];
    float gyf = (geom[(size_t)p * 3 + 1] - (bxp[1] - dxp[1] * 0.5f)) / dxp[1];
    float gzf = (geom[(size_t)p * 3 + 2] - (bxp[2] - dxp[2] * 0.5f)) / dxp[2];
    int gx = (int)gxf, gy = (int)gyf, gz = (int)gzf;
    if (gx < 0 || gx >= NX_ || gy < 0 || gy >= NY_ ||
        gz < 0 || gz >= NZ_) return;
    float val = x[(size_t)p * C_ + c];
    atomicAdd(&out[(((size_t)b * C_ + c) * NX_ + gx) * NY_ + gy], val);
}

// ---------------------------------------------------------------------------
extern "C" void kernel_launch(void* const* d_in, const int* in_sizes, int n_in,
                              void* d_out, int out_size, void* d_ws, size_t ws_size,
                              hipStream_t stream)
{
    const float* x    = (const float*)d_in[0];   // (B,N,D,H,W,C)
    const float* geom = (const float*)d_in[1];   // (B,N,D,H,W,3)
    const float* sem  = (const float*)d_in[2];   // (B*N,2,H,W)
    const float* dxp  = (const float*)d_in[3];   // (3,)
    const float* bxp  = (const float*)d_in[4];   // (3,)
    float* out = (float*)d_out;                  // (B, C, NX, NY)

    // ws layout (1 MiB-aligned regions; total need ~10.5 MiB)
    char* wsb = (char*)d_ws;
    const size_t MB = 1024 * 1024;
    int* counts   = (int*)(wsb + 0 * MB);   // NVOX ints        (640 KB)
    int* base     = (int*)(wsb + 1 * MB);   // NVOX+1 ints      (640 KB)
    int* cursor   = (int*)(wsb + 2 * MB);   // NVOX ints        (640 KB)
    int* partials = (int*)(wsb + 3 * MB);   // 625 ints
    int* voxid    = (int*)(wsb + 4 * MB);   // NPRIME ints      (2.1 MB)
    int* plist    = (int*)(wsb + 7 * MB);   // NPRIME ints      (2.1 MB)
    const size_t wsNeed = 10 * MB;

    if (ws_size >= wsNeed) {
        hipMemsetAsync(counts, 0, (size_t)NVOX * sizeof(int), stream);
        hist_kernel<<<NPRIME / 256, 256, 0, stream>>>(geom, sem, dxp, bxp,
                                                      voxid, counts);
        scan1_kernel<<<NVOX / 256, 256, 0, stream>>>(counts, base, partials);
        scan2_kernel<<<1, 1024, 0, stream>>>(partials, base);
        scan3_kernel<<<NVOX / 256, 256, 0, stream>>>(base, partials, cursor);
        fill_kernel<<<NPRIME / 256, 256, 0, stream>>>(voxid, cursor, plist);
        gather_kernel<<<NVOX / 64, 256, 0, stream>>>(x, base, plist, out);
    } else {
        hipMemsetAsync(out, 0, (size_t)B_ * C_ * NXY * sizeof(float), stream);
        int nBlocks = (NPRIME * 64 + 255) / 256;
        scatter_direct<<<nBlocks, 256, 0, stream>>>(x, geom, sem, dxp, bxp, out);
    }
}